// Round 8
// baseline (215.805 us; speedup 1.0000x reference)
//
#include <hip/hip_runtime.h>

// MoE GLU MLP: E=8, D=1024, H=1024, K=2, N=2048 tokens, 4096 pairs.
// R15 = R14 with BM 64->128 in both GEMMs (counted-vmcnt 2-phase kept):
//   gemm1: 128m x 64 out-cols; 4 waves each own 32 rows x all 64 cols;
//          32 MFMA/wave/K-step vs 8 staged loads (was 16:6). LDS 2x32KB.
//   gemm2: 128m x 64n, 2 buffers (2x24KB, 3 blocks/CU), vmcnt(6).
//   B-panel re-staging traffic halves; ~512 active blocks (2/CU).
//   gemm1 aux: 512 blocks x 2 tcvt2 W2 tiles (barrier between).
// prep (tcvt2 W1-cvt, x-cvt, out-zero, bucket) unchanged from R14.

typedef __bf16 bf16x8 __attribute__((ext_vector_type(8)));
typedef __bf16 bf16x4 __attribute__((ext_vector_type(4)));
typedef float  f32x4  __attribute__((ext_vector_type(4)));

#define NPAIR 4096
#define NTOK  2048
#define DDIM  1024
#define HDIM  1024
#define NEXP  8

// workspace layout (bytes)
#define ORDER_I   64                      // int index of order[] in wsi
#define XB_OFF    (24576)                 // bf16 x        [2048][1024]   4 MB
#define W1T_OFF   (XB_OFF + 4194304)      // bf16 W1^T  [8][2048][1024]  32 MB
#define W2T_OFF   (W1T_OFF + 33554432)    // bf16 W2^T  [8][1024][1024]  16 MB
#define ACT_OFF   (W2T_OFF + 16777216)    // bf16 act      [5120][1024] 10.5 MB

#define GLOAD_LDS16(g, l) \
    __builtin_amdgcn_global_load_lds( \
        (const __attribute__((address_space(1))) void*)(g), \
        (__attribute__((address_space(3))) void*)(l), 16, 0, 0)

// 64k x 128c transpose-convert: global_load_lds stage -> one barrier ->
// 8x ds_read_b128 per thread -> reg 8x4 transpose -> bf16x8 stores.
// tt = 32KB fp32 [64][128]. d[(c0+n)*R + k] = s[k][c0+n] cast to bf16.
__device__ __forceinline__ void tcvt2(const float* __restrict__ s,
                                      __bf16* __restrict__ d,
                                      int R, int C, int k0, int c0,
                                      float* tt, int tid) {
#pragma unroll
    for (int j = 0; j < 8; j++) {
        int c = j * 256 + tid;
        int row = c >> 5, col = (c & 31) * 4;
        GLOAD_LDS16(s + (size_t)(k0 + row) * C + c0 + col, (char*)tt + c * 16);
    }
    __syncthreads();                       // drains vmcnt(0) + barrier
    const int a = tid >> 5, b = tid & 31;  // a: k-block of 8, b: col-block of 4
    f32x4 v[8];
#pragma unroll
    for (int jj = 0; jj < 8; jj++)
        v[jj] = *(const f32x4*)(tt + (8 * a + jj) * 128 + 4 * b);
#pragma unroll
    for (int ii = 0; ii < 4; ii++) {
        bf16x8 o;
#pragma unroll
        for (int jj = 0; jj < 8; jj++) o[jj] = (__bf16)v[jj][ii];
        *(bf16x8*)(d + (size_t)(c0 + 4 * b + ii) * R + k0 + 8 * a) = o;
    }
}

// ---- prep: W1-cvt (2048) + x-cvt (256) + out-zero (512) + bucket (8) ----
__global__ __launch_bounds__(256) void prep_kernel(const float* __restrict__ x,
                                                   const float* __restrict__ W1,
                                                   const int* __restrict__ idx,
                                                   int* __restrict__ wsi,
                                                   __bf16* __restrict__ xb,
                                                   __bf16* __restrict__ w1t,
                                                   float* __restrict__ out) {
    __shared__ __align__(16) float tt[64 * 128];
    __shared__ int cnt[NEXP];
    __shared__ int sbase, scur;
    const int b = blockIdx.x;
    const int tid = threadIdx.x;
    if (b < 2048) {
        int e = b >> 8, t2 = b & 255;
        int k0 = (t2 & 15) * 64, c0 = (t2 >> 4) * 128;
        tcvt2(W1 + (size_t)e * DDIM * 2 * HDIM, w1t + (size_t)e * 2 * HDIM * DDIM,
              DDIM, 2 * HDIM, k0, c0, tt, tid);
    } else if (b < 2304) {
        size_t base = (size_t)(b - 2048) * 8192 + tid * 8;
#pragma unroll
        for (int j = 0; j < 4; j++) {
            const float* sp = x + base + j * 2048;
            f32x4 v0 = *(const f32x4*)sp;
            f32x4 v1 = *(const f32x4*)(sp + 4);
            bf16x8 o;
            o[0] = (__bf16)v0[0]; o[1] = (__bf16)v0[1]; o[2] = (__bf16)v0[2]; o[3] = (__bf16)v0[3];
            o[4] = (__bf16)v1[0]; o[5] = (__bf16)v1[1]; o[6] = (__bf16)v1[2]; o[7] = (__bf16)v1[3];
            *(bf16x8*)(xb + base + j * 2048) = o;
        }
    } else if (b < 2816) {
        int zb = b - 2304;                   // 512 blocks zero 8 MB of out
        float4 z4 = {0.f, 0.f, 0.f, 0.f};
        int b4 = zb * 4096;
#pragma unroll
        for (int j = 0; j < 4; j++)
            *(float4*)(out + b4 + j * 1024 + tid * 4) = z4;
    } else {
        const int e = b - 2816;
        if (tid < NEXP) cnt[tid] = 0;
        if (tid == 0) scur = 0;
        __syncthreads();
        for (int i = tid; i < NPAIR; i += 256) atomicAdd(&cnt[idx[i] & 7], 1);
        __syncthreads();
        if (tid == 0) {
            int off = 0;
            for (int e2 = 0; e2 < NEXP; e2++) {
                if (e2 == e) { wsi[e] = cnt[e]; wsi[8 + e] = off; sbase = off; }
                off += (cnt[e2] + 127) & ~127;
            }
        }
        __syncthreads();
        for (int i = tid; i < NPAIR; i += 256) {
            if ((idx[i] & 7) == e) {
                int s = atomicAdd(&scur, 1);
                wsi[ORDER_I + sbase + s] = i;
            }
        }
    }
}

// ---------------- gemm1: 128m x 64 out-cols (z<8) + aux W2-cvt (z==8) ----------------
__global__ __launch_bounds__(256) void gemm1_kernel(const __bf16* __restrict__ xb,
                                                    const __bf16* __restrict__ w1t,
                                                    const int* __restrict__ wsi,
                                                    __bf16* __restrict__ act,
                                                    const float* __restrict__ W2,
                                                    __bf16* __restrict__ w2t) {
    __shared__ __align__(16) char smem[65536];   // GEMM: 2 x (As 16K | Bs 16K); aux: 32K fp32
    const int tid = threadIdx.x;
    const int z = blockIdx.z;

    if (z >= 8) {                                // 512 blocks x 2 W2-cvt tiles (64k x 128c)
        int aux = blockIdx.y * 16 + blockIdx.x;  // 0..511
#pragma unroll
        for (int tt2 = 0; tt2 < 2; tt2++) {
            int tile = aux * 2 + tt2;            // 0..1023
            int e = tile >> 7, t2 = tile & 127;
            int k0 = (t2 & 15) * 64, c0 = (t2 >> 4) * 128;
            tcvt2(W2 + (size_t)e * HDIM * DDIM, w2t + (size_t)e * DDIM * HDIM,
                  HDIM, DDIM, k0, c0, (float*)smem, tid);
            if (tt2 == 0) __syncthreads();       // tt reuse fence
        }
        return;
    }

    const int e = z;
    const int cnt = wsi[e];
    const int m0 = blockIdx.y * 128;
    if (m0 >= cnt) return;
    const int base = wsi[8 + e];
    const int n0 = blockIdx.x * 64;
    const int* order = wsi + ORDER_I;
    const __bf16* w1e = w1t + (size_t)e * 2048 * 1024;

    const int lane = tid & 63, w = tid >> 6;
    const int lm = lane & 15, q = lane >> 4;
    const int wm = w;                            // 4 waves x 32 rows each
    const int x7 = lm & 7;
    const int sw0 = (q ^ x7) * 16;
    const int sw1 = ((4 + q) ^ x7) * 16;

    const __bf16* ga[4];
    const __bf16* gb[4];
#pragma unroll
    for (int j = 0; j < 4; j++) {
        int c = j * 256 + tid;                   // 0..1023
        int r = c >> 3;                          // 0..127
        int ks = ((c & 7) ^ (r & 7)) * 8;
        int m = m0 + r; if (m >= cnt) m = cnt - 1;
        int tok = order[base + m] >> 1;
        ga[j] = xb + (size_t)tok * DDIM + ks;
    }
#pragma unroll
    for (int j = 0; j < 4; j++) {
        int c = j * 256 + tid;
        int r = c >> 3;
        int ks = ((c & 7) ^ (r & 7)) * 8;
        int half = r >> 6, rr = r & 63;
        int rb = (rr < 32) ? (n0 + half * 32 + rr)
                           : (HDIM + n0 + half * 32 + (rr - 32));
        gb[j] = w1e + (size_t)rb * DDIM + ks;
    }

    f32x4 acch[2][4], accg[2][4];
#pragma unroll
    for (int mt = 0; mt < 2; mt++)
#pragma unroll
        for (int c = 0; c < 4; c++) {
            acch[mt][c] = (f32x4){0.f, 0.f, 0.f, 0.f};
            accg[mt][c] = (f32x4){0.f, 0.f, 0.f, 0.f};
        }

    // ---- prologue: issue tile 0 into buf0 (no drain) ----
#pragma unroll
    for (int j = 0; j < 4; j++) {
        GLOAD_LDS16(ga[j], smem + (j * 256 + tid) * 16);
        ga[j] += 64;
    }
#pragma unroll
    for (int j = 0; j < 4; j++) {
        GLOAD_LDS16(gb[j], smem + 16384 + (j * 256 + tid) * 16);
        gb[j] += 64;
    }

    // ---- 2-phase main loop, counted vmcnt ----
    for (int t = 0; t < 16; ++t) {
        char* cbase = smem + (t & 1) * 32768;
        if (t < 15) {
            char* nbase = smem + ((t + 1) & 1) * 32768;
#pragma unroll
            for (int j = 0; j < 4; j++) {
                GLOAD_LDS16(ga[j], nbase + (j * 256 + tid) * 16);
                ga[j] += 64;
            }
#pragma unroll
            for (int j = 0; j < 4; j++) {
                GLOAD_LDS16(gb[j], nbase + 16384 + (j * 256 + tid) * 16);
                gb[j] += 64;
            }
            asm volatile("s_waitcnt vmcnt(8)" ::: "memory");   // tile t landed
        } else {
            asm volatile("s_waitcnt vmcnt(0)" ::: "memory");
        }
        __builtin_amdgcn_s_barrier();
        __builtin_amdgcn_sched_barrier(0);
        __bf16 (*As)[64] = (__bf16 (*)[64])cbase;
        __bf16 (*Bs)[64] = (__bf16 (*)[64])(cbase + 16384);
#pragma unroll
        for (int kh = 0; kh < 2; kh++) {
            const int sw = kh ? sw1 : sw0;
            bf16x8 af[2];
#pragma unroll
            for (int mt = 0; mt < 2; mt++)
                af[mt] = *(const bf16x8*)((const char*)&As[wm * 32 + mt * 16 + lm][0] + sw);
            __builtin_amdgcn_s_setprio(1);
#pragma unroll
            for (int c = 0; c < 4; c++) {
                int hrow = (c >> 1) * 64 + (c & 1) * 16;       // h rows for col-group c
                bf16x8 bh = *(const bf16x8*)((const char*)&Bs[hrow + lm][0] + sw);
                bf16x8 bg = *(const bf16x8*)((const char*)&Bs[hrow + 32 + lm][0] + sw);
#pragma unroll
                for (int mt = 0; mt < 2; mt++) {
                    acch[mt][c] = __builtin_amdgcn_mfma_f32_16x16x32_bf16(af[mt], bh, acch[mt][c], 0, 0, 0);
                    accg[mt][c] = __builtin_amdgcn_mfma_f32_16x16x32_bf16(af[mt], bg, accg[mt][c], 0, 0, 0);
                }
            }
            __builtin_amdgcn_s_setprio(0);
        }
        __builtin_amdgcn_sched_barrier(0);
        __builtin_amdgcn_s_barrier();                // done reading buf[t&1]
    }

#pragma unroll
    for (int mt = 0; mt < 2; mt++) {
        int mbase = m0 + wm * 32 + mt * 16 + q * 4;
#pragma unroll
        for (int c = 0; c < 4; c++) {
            int col = n0 + c * 16 + lm;
#pragma unroll
            for (int r = 0; r < 4; r++) {
                int m = mbase + r;
                if (m < cnt) {
                    float h = acch[mt][c][r];
                    float g = accg[mt][c][r];
                    float a = h * (g / (1.f + __expf(-g)));
                    act[(size_t)(base + m) * HDIM + col] = (__bf16)a;
                }
            }
        }
    }
}

// ---------------- gemm2: 128m x 64n, counted vmcnt, fused atomic combine ----------------
__global__ __launch_bounds__(256) void gemm2_kernel(const __bf16* __restrict__ act,
                                                    const __bf16* __restrict__ w2t,
                                                    const int* __restrict__ wsi,
                                                    const float* __restrict__ p,
                                                    float* __restrict__ out) {
    const int e = blockIdx.z;
    const int cnt = wsi[e];
    const int m0 = blockIdx.y * 128;
    if (m0 >= cnt) return;
    const int base = wsi[8 + e];
    const int n0 = blockIdx.x * 64;
    const int* order = wsi + ORDER_I;
    const __bf16* w2e = w2t + (size_t)e * 1024 * 1024;

    __shared__ __align__(16) char smem[49152];   // 2 x (As 16K | Bs 8K)

    const int tid = threadIdx.x;
    const int lane = tid & 63, w = tid >> 6;
    const int lm = lane & 15, q = lane >> 4;
    const int wm = w;                            // 4 waves x 32 rows each
    const int x7 = lm & 7;
    const int sw0 = (q ^ x7) * 16;
    const int sw1 = ((4 + q) ^ x7) * 16;

    const __bf16* ga[4];
    const __bf16* gb[2];
#pragma unroll
    for (int j = 0; j < 4; j++) {
        int c = j * 256 + tid;                   // 0..1023
        int r = c >> 3;                          // 0..127
        int ks = ((c & 7) ^ (r & 7)) * 8;
        ga[j] = act + (size_t)(base + m0 + r) * HDIM + ks;   // pad rows masked at epilogue
    }
#pragma unroll
    for (int j = 0; j < 2; j++) {
        int c = j * 256 + tid;                   // 0..511
        int r = c >> 3;                          // 0..63
        int ks = ((c & 7) ^ (r & 7)) * 8;
        gb[j] = w2e + (size_t)(n0 + r) * HDIM + ks;
    }

    f32x4 acc[2][4];
#pragma unroll
    for (int mt = 0; mt < 2; mt++)
#pragma unroll
        for (int nt = 0; nt < 4; nt++) acc[mt][nt] = (f32x4){0.f, 0.f, 0.f, 0.f};

    // ---- prologue: issue tile 0 (no drain) ----
#pragma unroll
    for (int j = 0; j < 4; j++) {
        GLOAD_LDS16(ga[j], smem + (j * 256 + tid) * 16);
        ga[j] += 64;
    }
#pragma unroll
    for (int j = 0; j < 2; j++) {
        GLOAD_LDS16(gb[j], smem + 16384 + (j * 256 + tid) * 16);
        gb[j] += 64;
    }

    // ---- 2-phase main loop, counted vmcnt ----
    for (int t = 0; t < 16; ++t) {
        char* cbase = smem + (t & 1) * 24576;
        if (t < 15) {
            char* nbase = smem + ((t + 1) & 1) * 24576;
#pragma unroll
            for (int j = 0; j < 4; j++) {
                GLOAD_LDS16(ga[j], nbase + (j * 256 + tid) * 16);
                ga[j] += 64;
            }
#pragma unroll
            for (int j = 0; j < 2; j++) {
                GLOAD_LDS16(gb[j], nbase + 16384 + (j * 256 + tid) * 16);
                gb[j] += 64;
            }
            asm volatile("s_waitcnt vmcnt(6)" ::: "memory");   // tile t landed
        } else {
            asm volatile("s_waitcnt vmcnt(0)" ::: "memory");
        }
        __builtin_amdgcn_s_barrier();
        __builtin_amdgcn_sched_barrier(0);
        __bf16 (*As)[64] = (__bf16 (*)[64])cbase;
        __bf16 (*Bs)[64] = (__bf16 (*)[64])(cbase + 16384);
#pragma unroll
        for (int kh = 0; kh < 2; kh++) {
            const int sw = kh ? sw1 : sw0;
            bf16x8 af[2];
#pragma unroll
            for (int mt = 0; mt < 2; mt++)
                af[mt] = *(const bf16x8*)((const char*)&As[wm * 32 + mt * 16 + lm][0] + sw);
            __builtin_amdgcn_s_setprio(1);
#pragma unroll
            for (int nt = 0; nt < 4; nt++) {
                bf16x8 bfr = *(const bf16x8*)((const char*)&Bs[nt * 16 + lm][0] + sw);
#pragma unroll
                for (int mt = 0; mt < 2; mt++)
                    acc[mt][nt] = __builtin_amdgcn_mfma_f32_16x16x32_bf16(af[mt], bfr, acc[mt][nt], 0, 0, 0);
            }
            __builtin_amdgcn_s_setprio(0);
        }
        __builtin_amdgcn_sched_barrier(0);
        __builtin_amdgcn_s_barrier();                // done reading buf[t&1]
    }

    int pi[2][4];
    float pw[2][4];
#pragma unroll
    for (int mt = 0; mt < 2; mt++)
#pragma unroll
        for (int r = 0; r < 4; r++) {
            int gm = m0 + wm * 32 + mt * 16 + q * 4 + r;
            if (gm < cnt) {
                int pr = order[base + gm];
                pi[mt][r] = pr;
                pw[mt][r] = p[pr];
            } else pi[mt][r] = -1;
        }
#pragma unroll
    for (int mt = 0; mt < 2; mt++)
#pragma unroll
        for (int nt = 0; nt < 4; nt++) {
            int col = n0 + nt * 16 + lm;
#pragma unroll
            for (int r = 0; r < 4; r++) {
                if (pi[mt][r] >= 0) {
                    int tok = pi[mt][r] >> 1;
                    atomicAdd(out + (size_t)tok * DDIM + col, pw[mt][r] * acc[mt][nt][r]);
                }
            }
        }
}

extern "C" void kernel_launch(void* const* d_in, const int* in_sizes, int n_in,
                              void* d_out, int out_size, void* d_ws, size_t ws_size,
                              hipStream_t stream) {
    (void)in_sizes; (void)n_in; (void)out_size; (void)ws_size;
    const float* x   = (const float*)d_in[0];
    const float* p   = (const float*)d_in[1];
    const int* eidx  = (const int*)d_in[2];
    const float* W1  = (const float*)d_in[3];
    const float* W2  = (const float*)d_in[4];
    float* out = (float*)d_out;

    char* ws = (char*)d_ws;
    int* wsi     = (int*)ws;
    __bf16* xb   = (__bf16*)(ws + XB_OFF);
    __bf16* w1t  = (__bf16*)(ws + W1T_OFF);
    __bf16* w2t  = (__bf16*)(ws + W2T_OFF);
    __bf16* act  = (__bf16*)(ws + ACT_OFF);

    // 2048 W1-cvt + 256 x-cvt + 512 out-zero + 8 bucket
    prep_kernel<<<2824, 256, 0, stream>>>(x, W1, eidx, wsi, xb, w1t, out);
    // z<8: gemm1 (128m tiles); z==8: 512 blocks x 2 W2-cvt tiles
    gemm1_kernel<<<dim3(16, 32, 9), 256, 0, stream>>>(xb, w1t, wsi, act, W2, w2t);
    gemm2_kernel<<<dim3(16, 32, NEXP), 256, 0, stream>>>(act, w2t, wsi, p, out);
}

// Round 9
// 204.809 us; speedup vs baseline: 1.0537x; 1.0537x over previous
//
#include <hip/hip_runtime.h>

// MoE GLU MLP: E=8, D=1024, H=1024, K=2, N=2048 tokens, 4096 pairs.
// R16 = consolidation on the best measured config (R12, 200.5us) + aux-first:
//   - gemm1: 64x64 tiles, dbuf 48KB, counted vmcnt(6) 2-phase (R12 exact).
//     aux W2-cvt moved to z=0 (GEMM at z=1..8): HW dispatches blocks in linear
//     order, so aux now OVERLAPS the GEMM phase instead of tailing it (R12-R15
//     had aux at z>=8 => ~1024 short blocks serialized after GEMM drained).
//   - gemm2: R12 exact (64x64, 2x16KB, vmcnt(4)).
//   - prep: R14's tcvt2 version (W1-cvt 2048, x-cvt 256, out-zero 512, bucket 8).

typedef __bf16 bf16x8 __attribute__((ext_vector_type(8)));
typedef __bf16 bf16x4 __attribute__((ext_vector_type(4)));
typedef float  f32x4  __attribute__((ext_vector_type(4)));

#define NPAIR 4096
#define NTOK  2048
#define DDIM  1024
#define HDIM  1024
#define NEXP  8

// workspace layout (bytes)
#define ORDER_I   64                      // int index of order[] in wsi
#define XB_OFF    (24576)                 // bf16 x        [2048][1024]   4 MB
#define W1T_OFF   (XB_OFF + 4194304)      // bf16 W1^T  [8][2048][1024]  32 MB
#define W2T_OFF   (W1T_OFF + 33554432)    // bf16 W2^T  [8][1024][1024]  16 MB
#define ACT_OFF   (W2T_OFF + 16777216)    // bf16 act      [5120][1024] 10.5 MB

#define GLOAD_LDS16(g, l) \
    __builtin_amdgcn_global_load_lds( \
        (const __attribute__((address_space(1))) void*)(g), \
        (__attribute__((address_space(3))) void*)(l), 16, 0, 0)

// 64k x 128c transpose-convert: global_load_lds stage -> one barrier ->
// 8x ds_read_b128 per thread -> reg 8x4 transpose -> bf16x8 stores.
// tt = 32KB fp32 [64][128]. d[(c0+n)*R + k] = s[k][c0+n] cast to bf16.
__device__ __forceinline__ void tcvt2(const float* __restrict__ s,
                                      __bf16* __restrict__ d,
                                      int R, int C, int k0, int c0,
                                      float* tt, int tid) {
#pragma unroll
    for (int j = 0; j < 8; j++) {
        int c = j * 256 + tid;
        int row = c >> 5, col = (c & 31) * 4;
        GLOAD_LDS16(s + (size_t)(k0 + row) * C + c0 + col, (char*)tt + c * 16);
    }
    __syncthreads();                       // drains vmcnt(0) + barrier
    const int a = tid >> 5, b = tid & 31;  // a: k-block of 8, b: col-block of 4
    f32x4 v[8];
#pragma unroll
    for (int jj = 0; jj < 8; jj++)
        v[jj] = *(const f32x4*)(tt + (8 * a + jj) * 128 + 4 * b);
#pragma unroll
    for (int ii = 0; ii < 4; ii++) {
        bf16x8 o;
#pragma unroll
        for (int jj = 0; jj < 8; jj++) o[jj] = (__bf16)v[jj][ii];
        *(bf16x8*)(d + (size_t)(c0 + 4 * b + ii) * R + k0 + 8 * a) = o;
    }
}

// ---- prep: W1-cvt (2048) + x-cvt (256) + out-zero (512) + bucket (8) ----
__global__ __launch_bounds__(256) void prep_kernel(const float* __restrict__ x,
                                                   const float* __restrict__ W1,
                                                   const int* __restrict__ idx,
                                                   int* __restrict__ wsi,
                                                   __bf16* __restrict__ xb,
                                                   __bf16* __restrict__ w1t,
                                                   float* __restrict__ out) {
    __shared__ __align__(16) float tt[64 * 128];
    __shared__ int cnt[NEXP];
    __shared__ int sbase, scur;
    const int b = blockIdx.x;
    const int tid = threadIdx.x;
    if (b < 2048) {
        int e = b >> 8, t2 = b & 255;
        int k0 = (t2 & 15) * 64, c0 = (t2 >> 4) * 128;
        tcvt2(W1 + (size_t)e * DDIM * 2 * HDIM, w1t + (size_t)e * 2 * HDIM * DDIM,
              DDIM, 2 * HDIM, k0, c0, tt, tid);
    } else if (b < 2304) {
        size_t base = (size_t)(b - 2048) * 8192 + tid * 8;
#pragma unroll
        for (int j = 0; j < 4; j++) {
            const float* sp = x + base + j * 2048;
            f32x4 v0 = *(const f32x4*)sp;
            f32x4 v1 = *(const f32x4*)(sp + 4);
            bf16x8 o;
            o[0] = (__bf16)v0[0]; o[1] = (__bf16)v0[1]; o[2] = (__bf16)v0[2]; o[3] = (__bf16)v0[3];
            o[4] = (__bf16)v1[0]; o[5] = (__bf16)v1[1]; o[6] = (__bf16)v1[2]; o[7] = (__bf16)v1[3];
            *(bf16x8*)(xb + base + j * 2048) = o;
        }
    } else if (b < 2816) {
        int zb = b - 2304;                   // 512 blocks zero 8 MB of out
        float4 z4 = {0.f, 0.f, 0.f, 0.f};
        int b4 = zb * 4096;
#pragma unroll
        for (int j = 0; j < 4; j++)
            *(float4*)(out + b4 + j * 1024 + tid * 4) = z4;
    } else {
        const int e = b - 2816;
        if (tid < NEXP) cnt[tid] = 0;
        if (tid == 0) scur = 0;
        __syncthreads();
        for (int i = tid; i < NPAIR; i += 256) atomicAdd(&cnt[idx[i] & 7], 1);
        __syncthreads();
        if (tid == 0) {
            int off = 0;
            for (int e2 = 0; e2 < NEXP; e2++) {
                if (e2 == e) { wsi[e] = cnt[e]; wsi[8 + e] = off; sbase = off; }
                off += (cnt[e2] + 127) & ~127;
            }
        }
        __syncthreads();
        for (int i = tid; i < NPAIR; i += 256) {
            if ((idx[i] & 7) == e) {
                int s = atomicAdd(&scur, 1);
                wsi[ORDER_I + sbase + s] = i;
            }
        }
    }
}

// ---------------- gemm1: aux W2-cvt (z==0, dispatches FIRST) + 64m x 64 out-cols (z>=1) ----------------
__global__ __launch_bounds__(256) void gemm1_kernel(const __bf16* __restrict__ xb,
                                                    const __bf16* __restrict__ w1t,
                                                    const int* __restrict__ wsi,
                                                    __bf16* __restrict__ act,
                                                    const float* __restrict__ W2,
                                                    __bf16* __restrict__ w2t) {
    __shared__ __align__(16) char smem[49152];   // GEMM: 2 x (As 8K | Bs 16K); aux: 32K fp32
    const int tid = threadIdx.x;
    const int z = blockIdx.z;

    if (z == 0) {                                // 1024 W2-cvt tiles (64k x 128c), overlap w/ GEMM
        int aux = blockIdx.y * 16 + blockIdx.x;
        int e = aux >> 7, t2 = aux & 127;
        int k0 = (t2 & 15) * 64, c0 = (t2 >> 4) * 128;
        tcvt2(W2 + (size_t)e * HDIM * DDIM, w2t + (size_t)e * DDIM * HDIM,
              HDIM, DDIM, k0, c0, (float*)smem, tid);
        return;
    }

    const int e = z - 1;
    const int cnt = wsi[e];
    const int m0 = blockIdx.y * 64;
    if (m0 >= cnt) return;
    const int base = wsi[8 + e];
    const int n0 = blockIdx.x * 64;
    const int* order = wsi + ORDER_I;
    const __bf16* w1e = w1t + (size_t)e * 2048 * 1024;

    const int lane = tid & 63, w = tid >> 6;
    const int lm = lane & 15, q = lane >> 4;
    const int wm = w & 1, wn = w >> 1;
    const int x7 = lm & 7;
    const int sw0 = (q ^ x7) * 16;
    const int sw1 = ((4 + q) ^ x7) * 16;

    const __bf16* ga[2];
    const __bf16* gb[4];
#pragma unroll
    for (int j = 0; j < 2; j++) {
        int c = j * 256 + tid;
        int r = c >> 3;
        int ks = ((c & 7) ^ (r & 7)) * 8;
        int m = m0 + r; if (m >= cnt) m = cnt - 1;
        int tok = order[base + m] >> 1;
        ga[j] = xb + (size_t)tok * DDIM + ks;
    }
#pragma unroll
    for (int j = 0; j < 4; j++) {
        int c = j * 256 + tid;
        int r = c >> 3;
        int ks = ((c & 7) ^ (r & 7)) * 8;
        int half = r >> 6, rr = r & 63;
        int rb = (rr < 32) ? (n0 + half * 32 + rr)
                           : (HDIM + n0 + half * 32 + (rr - 32));
        gb[j] = w1e + (size_t)rb * DDIM + ks;
    }

    f32x4 acc[2][4];
#pragma unroll
    for (int mt = 0; mt < 2; mt++)
#pragma unroll
        for (int nt = 0; nt < 4; nt++) acc[mt][nt] = (f32x4){0.f, 0.f, 0.f, 0.f};

    // ---- prologue: issue tile 0 into buf0 (no drain) ----
#pragma unroll
    for (int j = 0; j < 2; j++) {
        GLOAD_LDS16(ga[j], smem + (j * 256 + tid) * 16);
        ga[j] += 64;
    }
#pragma unroll
    for (int j = 0; j < 4; j++) {
        GLOAD_LDS16(gb[j], smem + 8192 + (j * 256 + tid) * 16);
        gb[j] += 64;
    }

    // ---- 2-phase main loop, counted vmcnt: tile t+1 stays in flight ----
    for (int t = 0; t < 16; ++t) {
        char* cbase = smem + (t & 1) * 24576;
        if (t < 15) {
            char* nbase = smem + ((t + 1) & 1) * 24576;
#pragma unroll
            for (int j = 0; j < 2; j++) {
                GLOAD_LDS16(ga[j], nbase + (j * 256 + tid) * 16);
                ga[j] += 64;
            }
#pragma unroll
            for (int j = 0; j < 4; j++) {
                GLOAD_LDS16(gb[j], nbase + 8192 + (j * 256 + tid) * 16);
                gb[j] += 64;
            }
            asm volatile("s_waitcnt vmcnt(6)" ::: "memory");   // tile t landed
        } else {
            asm volatile("s_waitcnt vmcnt(0)" ::: "memory");
        }
        __builtin_amdgcn_s_barrier();
        __builtin_amdgcn_sched_barrier(0);
        __bf16 (*As)[64] = (__bf16 (*)[64])cbase;
        __bf16 (*Bs)[64] = (__bf16 (*)[64])(cbase + 8192);
#pragma unroll
        for (int kh = 0; kh < 2; kh++) {
            const int sw = kh ? sw1 : sw0;
            bf16x8 af[2];
#pragma unroll
            for (int mt = 0; mt < 2; mt++)
                af[mt] = *(const bf16x8*)((const char*)&As[wm * 32 + mt * 16 + lm][0] + sw);
            __builtin_amdgcn_s_setprio(1);
#pragma unroll
            for (int nt = 0; nt < 4; nt++) {
                bf16x8 bfr = *(const bf16x8*)((const char*)&Bs[wn * 64 + nt * 16 + lm][0] + sw);
#pragma unroll
                for (int mt = 0; mt < 2; mt++)
                    acc[mt][nt] = __builtin_amdgcn_mfma_f32_16x16x32_bf16(af[mt], bfr, acc[mt][nt], 0, 0, 0);
            }
            __builtin_amdgcn_s_setprio(0);
        }
        __builtin_amdgcn_sched_barrier(0);
        __builtin_amdgcn_s_barrier();                // done reading buf[t&1]
    }

#pragma unroll
    for (int mt = 0; mt < 2; mt++) {
        int mbase = m0 + wm * 32 + mt * 16 + q * 4;
#pragma unroll
        for (int ntp = 0; ntp < 2; ntp++) {
            int col = n0 + wn * 32 + ntp * 16 + lm;
#pragma unroll
            for (int r = 0; r < 4; r++) {
                int m = mbase + r;
                if (m < cnt) {
                    float h = acc[mt][ntp][r];
                    float g = acc[mt][ntp + 2][r];
                    float a = h * (g / (1.f + __expf(-g)));
                    act[(size_t)(base + m) * HDIM + col] = (__bf16)a;
                }
            }
        }
    }
}

// ---------------- gemm2: 64m x 64n, counted vmcnt, fused atomic combine ----------------
__global__ __launch_bounds__(256) void gemm2_kernel(const __bf16* __restrict__ act,
                                                    const __bf16* __restrict__ w2t,
                                                    const int* __restrict__ wsi,
                                                    const float* __restrict__ p,
                                                    float* __restrict__ out) {
    const int e = blockIdx.z;
    const int cnt = wsi[e];
    const int m0 = blockIdx.y * 64;
    if (m0 >= cnt) return;
    const int base = wsi[8 + e];
    const int n0 = blockIdx.x * 64;
    const int* order = wsi + ORDER_I;
    const __bf16* w2e = w2t + (size_t)e * 1024 * 1024;

    __shared__ __align__(16) char smem[32768];   // 2 x (As 8K | Bs 8K)

    const int tid = threadIdx.x;
    const int lane = tid & 63, w = tid >> 6;
    const int lm = lane & 15, q = lane >> 4;
    const int wm = w & 1, wn = w >> 1;
    const int x7 = lm & 7;
    const int sw0 = (q ^ x7) * 16;
    const int sw1 = ((4 + q) ^ x7) * 16;

    const __bf16* ga[2];
    const __bf16* gb[2];
#pragma unroll
    for (int j = 0; j < 2; j++) {
        int c = j * 256 + tid;
        int r = c >> 3;
        int ks = ((c & 7) ^ (r & 7)) * 8;
        ga[j] = act + (size_t)(base + m0 + r) * HDIM + ks;   // pad rows masked at epilogue
        gb[j] = w2e + (size_t)(n0 + r) * HDIM + ks;
    }

    f32x4 acc[2][2];
#pragma unroll
    for (int mt = 0; mt < 2; mt++)
#pragma unroll
        for (int nt = 0; nt < 2; nt++) acc[mt][nt] = (f32x4){0.f, 0.f, 0.f, 0.f};

    // ---- prologue: issue tile 0 (no drain) ----
#pragma unroll
    for (int j = 0; j < 2; j++) {
        GLOAD_LDS16(ga[j], smem + (j * 256 + tid) * 16);
        GLOAD_LDS16(gb[j], smem + 8192 + (j * 256 + tid) * 16);
        ga[j] += 64; gb[j] += 64;
    }

    // ---- 2-phase main loop, counted vmcnt ----
    for (int t = 0; t < 16; ++t) {
        char* cbase = smem + (t & 1) * 16384;
        if (t < 15) {
            char* nbase = smem + ((t + 1) & 1) * 16384;
#pragma unroll
            for (int j = 0; j < 2; j++) {
                GLOAD_LDS16(ga[j], nbase + (j * 256 + tid) * 16);
                GLOAD_LDS16(gb[j], nbase + 8192 + (j * 256 + tid) * 16);
                ga[j] += 64; gb[j] += 64;
            }
            asm volatile("s_waitcnt vmcnt(4)" ::: "memory");   // tile t landed
        } else {
            asm volatile("s_waitcnt vmcnt(0)" ::: "memory");
        }
        __builtin_amdgcn_s_barrier();
        __builtin_amdgcn_sched_barrier(0);
        __bf16 (*As)[64] = (__bf16 (*)[64])cbase;
        __bf16 (*Bs)[64] = (__bf16 (*)[64])(cbase + 8192);
#pragma unroll
        for (int kh = 0; kh < 2; kh++) {
            const int sw = kh ? sw1 : sw0;
            bf16x8 af[2];
#pragma unroll
            for (int mt = 0; mt < 2; mt++)
                af[mt] = *(const bf16x8*)((const char*)&As[wm * 32 + mt * 16 + lm][0] + sw);
            __builtin_amdgcn_s_setprio(1);
#pragma unroll
            for (int nt = 0; nt < 2; nt++) {
                bf16x8 bfr = *(const bf16x8*)((const char*)&Bs[wn * 32 + nt * 16 + lm][0] + sw);
#pragma unroll
                for (int mt = 0; mt < 2; mt++)
                    acc[mt][nt] = __builtin_amdgcn_mfma_f32_16x16x32_bf16(af[mt], bfr, acc[mt][nt], 0, 0, 0);
            }
            __builtin_amdgcn_s_setprio(0);
        }
        __builtin_amdgcn_sched_barrier(0);
        __builtin_amdgcn_s_barrier();                // done reading buf[t&1]
    }

    int pi[2][4];
    float pw[2][4];
#pragma unroll
    for (int mt = 0; mt < 2; mt++)
#pragma unroll
        for (int r = 0; r < 4; r++) {
            int gm = m0 + wm * 32 + mt * 16 + q * 4 + r;
            if (gm < cnt) {
                int pr = order[base + gm];
                pi[mt][r] = pr;
                pw[mt][r] = p[pr];
            } else pi[mt][r] = -1;
        }
#pragma unroll
    for (int mt = 0; mt < 2; mt++)
#pragma unroll
        for (int nt = 0; nt < 2; nt++) {
            int col = n0 + wn * 32 + nt * 16 + lm;
#pragma unroll
            for (int r = 0; r < 4; r++) {
                if (pi[mt][r] >= 0) {
                    int tok = pi[mt][r] >> 1;
                    atomicAdd(out + (size_t)tok * DDIM + col, pw[mt][r] * acc[mt][nt][r]);
                }
            }
        }
}

extern "C" void kernel_launch(void* const* d_in, const int* in_sizes, int n_in,
                              void* d_out, int out_size, void* d_ws, size_t ws_size,
                              hipStream_t stream) {
    (void)in_sizes; (void)n_in; (void)out_size; (void)ws_size;
    const float* x   = (const float*)d_in[0];
    const float* p   = (const float*)d_in[1];
    const int* eidx  = (const int*)d_in[2];
    const float* W1  = (const float*)d_in[3];
    const float* W2  = (const float*)d_in[4];
    float* out = (float*)d_out;

    char* ws = (char*)d_ws;
    int* wsi     = (int*)ws;
    __bf16* xb   = (__bf16*)(ws + XB_OFF);
    __bf16* w1t  = (__bf16*)(ws + W1T_OFF);
    __bf16* w2t  = (__bf16*)(ws + W2T_OFF);
    __bf16* act  = (__bf16*)(ws + ACT_OFF);

    // 2048 W1-cvt + 256 x-cvt + 512 out-zero + 8 bucket
    prep_kernel<<<2824, 256, 0, stream>>>(x, W1, eidx, wsi, xb, w1t, out);
    // z==0: 1024 W2-cvt tiles (dispatch first, overlap); z in [1,9): gemm1 64m tiles
    gemm1_kernel<<<dim3(16, 64, 9), 256, 0, stream>>>(xb, w1t, wsi, act, W2, w2t);
    gemm2_kernel<<<dim3(16, 64, NEXP), 256, 0, stream>>>(act, w2t, wsi, p, out);
}